// Round 1
// 912.892 us; speedup vs baseline: 1.1677x; 1.1677x over previous
//
#include <hip/hip_runtime.h>
#include <hip/hip_bf16.h>
#include <cstddef>

// Pipeline (internal math bf16 MFMA, fp32 accum; ~2% error budget >> bf16 err):
//   0)   convert X, Wq..Wo fp32 -> bf16 in ws (biases stay fp32)
//   1-2) Q/K = Xb @ W{q,k}b^T + b          (gemm128_bt<0> -> bf16 row-major)
//   3)   VT  = (Xb @ Wvb^T + bv)^T per head (gemm128_bt<2> -> bf16 [bh*64+d][SPAD])
//   4)   flash attention, KVBLK=64, V staged straight from VT (no in-kernel
//        transpose -> kills the 16-way LDS bank-conflict scatter)
//   5)   out = ctx @ Wob^T + bo            (gemm128_bt<1> -> fp32)
//
// R2 changes vs R1 (theory: attn 30% bank-conflict stall + GEMMs at ladder
// step-2):
//   - gemm128_bt: linear [128][32] LDS + __builtin_amdgcn_global_load_lds
//     width=16 (ladder m93->m97, +69% proven). OOB A-rows clamped per-lane.
//   - attn: KVBLK 32->64 (half the barriers/softmax reductions per key),
//     V pre-transposed globally, Ps padded to stride 72 (conflict-free),
//     XCD-chunked block swizzle for K/V L2 reuse.

using bf16x8 = __attribute__((ext_vector_type(8))) short;   // 8 bf16 = 4 VGPRs
using f32x4  = __attribute__((ext_vector_type(4))) float;   // MFMA accum

#define MFMA16(a, b, c) __builtin_amdgcn_mfma_f32_16x16x32_bf16((a), (b), (c), 0, 0, 0)

#define SLEN   577
#define NHEAD  12
#define DMODEL 768
#define SPAD   584    // VT row stride in keys: 584*2B = 1168B, 16B-aligned rows
#define NQT    10     // ceil(577/64) q-tiles

static __device__ __forceinline__ bf16x8 zero8() {
    bf16x8 z;
#pragma unroll
    for (int i = 0; i < 8; ++i) z[i] = 0;
    return z;
}

// async global->LDS, 16B per lane. LDS dest is wave-uniform base + lane*16.
static __device__ __forceinline__ void cp16_async(const __hip_bfloat16* g,
                                                  __hip_bfloat16* l) {
    __builtin_amdgcn_global_load_lds(
        (const __attribute__((address_space(1))) unsigned int*)g,
        (__attribute__((address_space(3))) unsigned int*)l,
        16, 0, 0);
}

// fp32 -> bf16, 8 elems/thread/iter, grid-stride. n8 = n/8 (all sizes %8==0).
__global__ __launch_bounds__(256) void cvt_f32_bf16(
    const float* __restrict__ in, __hip_bfloat16* __restrict__ out, int n8)
{
    int i = blockIdx.x * blockDim.x + threadIdx.x;
    const int stride = gridDim.x * blockDim.x;
    for (; i < n8; i += stride) {
        const float4* p = (const float4*)(in + (size_t)i * 8);
        float4 a = p[0], b = p[1];
        float f[8] = {a.x, a.y, a.z, a.w, b.x, b.y, b.z, b.w};
        bf16x8 o;
#pragma unroll
        for (int j = 0; j < 8; ++j) {
            __hip_bfloat16 h = __float2bfloat16(f[j]);
            o[j] = __builtin_bit_cast(short, h);
        }
        *(bf16x8*)(out + (size_t)i * 8) = o;
    }
}

// C = A[M,K] @ W[N,K]^T + bias[N]. 128x128 tile, BK=32, 4 waves 2x2.
// m97 structure: linear LDS (no padding -> global_load_lds legal), 2 barriers
// per K-step, compiler handles waitcnts.
// OMODE 0: bf16 row-major; 1: f32 row-major; 2: bf16 transposed per head into
// VT[((row/577)*768 + col)*SPAD + row%577]  (used for V).
template <int OMODE>
__global__ __launch_bounds__(256) void gemm128_bt(
    const __hip_bfloat16* __restrict__ A,
    const __hip_bfloat16* __restrict__ W,
    const float* __restrict__ bias,
    void* __restrict__ Cout,
    int M, int N, int K)
{
    __shared__ __hip_bfloat16 As[128][32];
    __shared__ __hip_bfloat16 Bs[128][32];

    const int tid  = threadIdx.x;
    const int lane = tid & 63;
    const int wave = tid >> 6;
    const int wm   = (wave >> 1) * 64;
    const int wn   = (wave & 1) * 64;
    const int quad = lane >> 4;
    const int low  = lane & 15;
    const int m0   = blockIdx.x * 128;
    const int n0   = blockIdx.y * 128;

    // staging: each wave-instr covers 16 rows x 32 cols (64 lanes x 16B),
    // LDS fill order == lane order (row lane/4, col (lane&3)*8) -> linear.
    const int srow = lane >> 2;
    const int scol = (lane & 3) * 8;

    const int ar0 = m0 + wave * 16 + srow;
    const int ar1 = ar0 + 64;
    // clamp OOB rows (last block only): finite garbage, masked at store.
    const __hip_bfloat16* Ag0 = A + (size_t)(ar0 < M ? ar0 : M - 1) * K + scol;
    const __hip_bfloat16* Ag1 = A + (size_t)(ar1 < M ? ar1 : M - 1) * K + scol;
    const __hip_bfloat16* Bg0 = W + (size_t)(n0 + wave * 16 + srow) * K + scol;
    const __hip_bfloat16* Bg1 = Bg0 + (size_t)64 * K;
    __hip_bfloat16* La0 = &As[wave * 16][0];
    __hip_bfloat16* La1 = &As[64 + wave * 16][0];
    __hip_bfloat16* Lb0 = &Bs[wave * 16][0];
    __hip_bfloat16* Lb1 = &Bs[64 + wave * 16][0];

    f32x4 acc[4][4] = {};

    for (int k0 = 0; k0 < K; k0 += 32) {
        cp16_async(Ag0 + k0, La0);
        cp16_async(Ag1 + k0, La1);
        cp16_async(Bg0 + k0, Lb0);
        cp16_async(Bg1 + k0, Lb1);
        __syncthreads();   // drains vmcnt -> staging visible

        bf16x8 af[4], bfv[4];
#pragma unroll
        for (int i = 0; i < 4; ++i)
            af[i] = *(const bf16x8*)&As[wm + i * 16 + low][quad * 8];
#pragma unroll
        for (int j = 0; j < 4; ++j)
            bfv[j] = *(const bf16x8*)&Bs[wn + j * 16 + low][quad * 8];
#pragma unroll
        for (int i = 0; i < 4; ++i)
#pragma unroll
            for (int j = 0; j < 4; ++j)
                acc[i][j] = MFMA16(af[i], bfv[j], acc[i][j]);
        __syncthreads();   // all reads done before next overwrite
    }

    // epilogue: C/D layout col=lane&15, row=quad*4+reg (m89-verified)
#pragma unroll
    for (int j = 0; j < 4; ++j) {
        const int col = n0 + wn + j * 16 + low;
        const float bv = bias[col];
#pragma unroll
        for (int i = 0; i < 4; ++i) {
#pragma unroll
            for (int r = 0; r < 4; ++r) {
                const int row = m0 + wm + i * 16 + quad * 4 + r;
                if (row < M) {
                    const float v = acc[i][j][r] + bv;
                    if constexpr (OMODE == 0) {
                        ((__hip_bfloat16*)Cout)[(size_t)row * N + col] =
                            __float2bfloat16(v);
                    } else if constexpr (OMODE == 1) {
                        ((float*)Cout)[(size_t)row * N + col] = v;
                    } else {
                        const int b = row / SLEN;       // magic-mul div
                        const int s = row - b * SLEN;
                        ((__hip_bfloat16*)Cout)
                            [((size_t)b * DMODEL + col) * SPAD + s] =
                            __float2bfloat16(v);
                    }
                }
            }
        }
    }
}

// Flash attention. Q/K layout [B*S, 768] (head h at cols h*64..); V comes in
// pre-transposed: VT row (bh*64 + d) holds keys 0..576 (stride SPAD).
// 1D grid 7680 = 8 XCDs x 960, XCD-chunked so one (b,h)'s 10 q-tiles share L2.
// Block 256 = 4 waves; wave w owns q rows q0+w*16..+15. KVBLK = 64.
__global__ __launch_bounds__(256) void attn_kernel(
    const __hip_bfloat16* __restrict__ Q,
    const __hip_bfloat16* __restrict__ Kk,
    const __hip_bfloat16* __restrict__ VT,
    __hip_bfloat16* __restrict__ O)
{
    const int bid = blockIdx.x;
    const int w   = (bid & 7) * 960 + (bid >> 3);   // 7680 = 8*960, bijective
    const int bh  = w / NQT;
    const int q0  = (w - bh * NQT) * 64;
    const int b   = bh / NHEAD;
    const int h   = bh - b * NHEAD;
    const int tid  = threadIdx.x;
    const int lane = tid & 63;
    const int wave = tid >> 6;
    const int quad = lane >> 4;
    const int low  = lane & 15;

    __shared__ __hip_bfloat16 Ks[64][72];      // keys x d   (stride 144B: 2-way max)
    __shared__ __hip_bfloat16 Vt[64][72];      // d x keys   (staged linear from VT)
    __shared__ __hip_bfloat16 Ps[4][16][72];   // per-wave P round-trip
                                               // (stride 72: quad offset 8q mod 32
                                               //  -> conflict-free scalar writes)

    const size_t base   = (size_t)b * SLEN * DMODEL + (size_t)h * 64;
    const size_t vtbase = (size_t)bh * 64 * SPAD;

    // Q A-frags: A[m=lane&15][k=quad*8+j], two k-steps for Dh=64
    const int qrow = q0 + wave * 16 + low;
    bf16x8 qf0 = zero8(), qf1 = zero8();
    if (qrow < SLEN) {
        qf0 = *(const bf16x8*)(Q + base + (size_t)qrow * DMODEL + quad * 8);
        qf1 = *(const bf16x8*)(Q + base + (size_t)qrow * DMODEL + 32 + quad * 8);
    }

    f32x4 acc[4] = {};           // ctx accum, 4 d-tiles
    float m_run[4], l_run[4];
#pragma unroll
    for (int r = 0; r < 4; ++r) { m_run[r] = -1e30f; l_run[r] = 0.f; }

    const int srow = tid >> 2;        // 0..63: key row (Ks) / d row (Vt)
    const int sc   = (tid & 3) * 16;  // 16-elem chunk

    for (int c0 = 0; c0 < SLEN; c0 += 64) {
        __syncthreads();   // previous iteration's readers done
        {   // stage K tile: row granularity guard, vector writes
            const int kg = c0 + srow;
            bf16x8 k0v = zero8(), k1v = zero8();
            if (kg < SLEN) {
                const __hip_bfloat16* p = Kk + base + (size_t)kg * DMODEL + sc;
                k0v = *(const bf16x8*)p;
                k1v = *(const bf16x8*)(p + 8);
            }
            *(bf16x8*)&Ks[srow][sc]     = k0v;
            *(bf16x8*)&Ks[srow][sc + 8] = k1v;
        }
        {   // stage V tile straight from VT (already [d][key]) - no transpose
            const __hip_bfloat16* p = VT + vtbase + (size_t)srow * SPAD + c0 + sc;
            bf16x8 v0, v1;
            if (c0 + sc + 15 < SLEN) {
                v0 = *(const bf16x8*)p;
                v1 = *(const bf16x8*)(p + 8);
            } else {            // boundary tile: zero-fill invalid keys (keep finite)
                v0 = zero8(); v1 = zero8();
#pragma unroll
                for (int j = 0; j < 8; ++j) {
                    if (c0 + sc + j < SLEN)
                        v0[j] = __builtin_bit_cast(short, p[j]);
                    if (c0 + sc + 8 + j < SLEN)
                        v1[j] = __builtin_bit_cast(short, p[8 + j]);
                }
            }
            *(bf16x8*)&Vt[srow][sc]     = v0;
            *(bf16x8*)&Vt[srow][sc + 8] = v1;
        }
        __syncthreads();

        // S = Q K^T  (four 16-key n-tiles, Dh=64 = 2 MFMA k-steps)
        f32x4 st[4] = {};
#pragma unroll
        for (int t = 0; t < 4; ++t) {
            bf16x8 kf0 = *(const bf16x8*)&Ks[t * 16 + low][quad * 8];
            bf16x8 kf1 = *(const bf16x8*)&Ks[t * 16 + low][32 + quad * 8];
            st[t] = MFMA16(qf0, kf0, st[t]);
            st[t] = MFMA16(qf1, kf1, st[t]);
        }
#pragma unroll
        for (int t = 0; t < 4; ++t) {
            const bool valid = (c0 + t * 16 + low) < SLEN;
#pragma unroll
            for (int r = 0; r < 4; ++r) {
                const float s = st[t][r] * 0.125f;   // 1/sqrt(64)
                st[t][r] = valid ? s : -1e30f;
            }
        }
        // online softmax; C-layout: reg r is row quad*4+r, col low.
        // Row lives in lanes quad*16..quad*16+15 -> shfl_xor 1,2,4,8.
#pragma unroll
        for (int r = 0; r < 4; ++r) {
            float mx = fmaxf(fmaxf(st[0][r], st[1][r]),
                             fmaxf(st[2][r], st[3][r]));
#pragma unroll
            for (int off = 1; off < 16; off <<= 1)
                mx = fmaxf(mx, __shfl_xor(mx, off));
            const float mnew  = fmaxf(m_run[r], mx);
            const float alpha = __expf(m_run[r] - mnew);
            float p[4], ps = 0.f;
#pragma unroll
            for (int t = 0; t < 4; ++t) {
                p[t] = __expf(st[t][r] - mnew);
                ps += p[t];
            }
#pragma unroll
            for (int off = 1; off < 16; off <<= 1)
                ps += __shfl_xor(ps, off);
            l_run[r] = l_run[r] * alpha + ps;
            m_run[r] = mnew;
#pragma unroll
            for (int dt = 0; dt < 4; ++dt) acc[dt][r] *= alpha;
#pragma unroll
            for (int t = 0; t < 4; ++t)
                Ps[wave][quad * 4 + r][t * 16 + low] = __float2bfloat16(p[t]);
        }
        // PV: A-frag of P from per-wave LDS (same-wave DS ops are in-order)
        bf16x8 pf0 = *(const bf16x8*)&Ps[wave][low][quad * 8];
        bf16x8 pf1 = *(const bf16x8*)&Ps[wave][low][32 + quad * 8];
#pragma unroll
        for (int dt = 0; dt < 4; ++dt) {
            bf16x8 vf0 = *(const bf16x8*)&Vt[dt * 16 + low][quad * 8];
            bf16x8 vf1 = *(const bf16x8*)&Vt[dt * 16 + low][32 + quad * 8];
            acc[dt] = MFMA16(pf0, vf0, acc[dt]);
            acc[dt] = MFMA16(pf1, vf1, acc[dt]);
        }
    }

#pragma unroll
    for (int dt = 0; dt < 4; ++dt) {
        const int col = h * 64 + dt * 16 + low;
#pragma unroll
        for (int r = 0; r < 4; ++r) {
            const int row = q0 + wave * 16 + quad * 4 + r;
            if (row < SLEN)
                O[((size_t)b * SLEN + row) * DMODEL + col] =
                    __float2bfloat16(acc[dt][r] / l_run[r]);
        }
    }
}

extern "C" void kernel_launch(void* const* d_in, const int* in_sizes, int n_in,
                              void* d_out, int out_size, void* d_ws, size_t ws_size,
                              hipStream_t stream) {
    const float* X  = (const float*)d_in[0];
    const float* Wq = (const float*)d_in[1];
    const float* bq = (const float*)d_in[2];
    const float* Wk = (const float*)d_in[3];
    const float* bk = (const float*)d_in[4];
    const float* Wv = (const float*)d_in[5];
    const float* bv = (const float*)d_in[6];
    const float* Wo = (const float*)d_in[7];
    const float* bo = (const float*)d_in[8];

    const int Bb = 64, S = SLEN, D = DMODEL;
    const int M = Bb * S;                       // 36928
    const size_t szX  = (size_t)M * D;          // 28,311,552
    const size_t szW  = (size_t)D * D;          // 589,824
    const size_t szVT = (size_t)Bb * NHEAD * 64 * SPAD;  // 28,704,768

    // ws layout (bf16): Xb | Wqb | Wkb | Wvb | Wob | Qb | Kb | VTb ; ctx aliases Xb
    __hip_bfloat16* Xb  = (__hip_bfloat16*)d_ws;
    __hip_bfloat16* Wqb = Xb + szX;
    __hip_bfloat16* Wkb = Wqb + szW;
    __hip_bfloat16* Wvb = Wkb + szW;
    __hip_bfloat16* Wob = Wvb + szW;
    __hip_bfloat16* Qb  = Wob + szW;
    __hip_bfloat16* Kb  = Qb + szX;
    __hip_bfloat16* VTb = Kb + szX;
    __hip_bfloat16* Cx  = Xb;                   // reuse after QKV gemms
    float* out = (float*)d_out;

    dim3 blk(256);
    cvt_f32_bf16<<<2048, blk, 0, stream>>>(X, Xb, (int)(szX / 8));
    cvt_f32_bf16<<<288,  blk, 0, stream>>>(Wq, Wqb, (int)(szW / 8));
    cvt_f32_bf16<<<288,  blk, 0, stream>>>(Wk, Wkb, (int)(szW / 8));
    cvt_f32_bf16<<<288,  blk, 0, stream>>>(Wv, Wvb, (int)(szW / 8));
    cvt_f32_bf16<<<288,  blk, 0, stream>>>(Wo, Wob, (int)(szW / 8));

    dim3 gG((M + 127) / 128, D / 128);          // 289 x 6
    gemm128_bt<0><<<gG, blk, 0, stream>>>(Xb, Wqb, bq, (void*)Qb,  M, D, D);
    gemm128_bt<0><<<gG, blk, 0, stream>>>(Xb, Wkb, bk, (void*)Kb,  M, D, D);
    gemm128_bt<2><<<gG, blk, 0, stream>>>(Xb, Wvb, bv, (void*)VTb, M, D, D);

    attn_kernel<<<dim3(Bb * NHEAD * NQT), blk, 0, stream>>>(Qb, Kb, VTb, Cx);

    gemm128_bt<1><<<gG, blk, 0, stream>>>(Cx, Wob, bo, (void*)out, M, D, D);
}

// Round 3
// 830.503 us; speedup vs baseline: 1.2836x; 1.0992x over previous
//
#include <hip/hip_runtime.h>
#include <hip/hip_bf16.h>
#include <cstddef>

// Pipeline (internal math bf16 MFMA, fp32 accum):
//   0)   convert X, Wq..Wo fp32 -> bf16 in ws (biases stay fp32)
//   1-2) Q/K = Xb @ W{q,k}b^T + b          (gemm128_bt<0> -> bf16 row-major)
//   3)   VT  = (Xb @ Wvb^T + bv)^T per head (gemm128_bt<2> -> bf16 [bh*64+d][SPAD])
//   4)   flash attention, KVBLK=64, V staged straight from VT
//   5)   out = ctx @ Wob^T + bo            (gemm128_bt<1> -> fp32)
//
// R3 = R1 (passed, 913us) + EXACTLY ONE change (bisection after R2's fail):
//   attn QK^T operands swapped (mfma(K,Q)) -> lane owns one q-row's 16 scores
//   in-register; softmax = in-lane 15-fmax tree + 2 cross-quad shfl (max),
//   in-lane f32 sum + 2 shfl (denominator), scalar m_run/l_run per lane,
//   4 shfl to broadcast alpha to the acc layout. Same numerics as R1
//   (f32 *0.125 post-MFMA, __expf, unconditional rescale, per-key mask).
//   R2's other five simultaneous changes (exp2-fold, defer-rescale, ones-MFMA,
//   in-LDS V transpose, fused gemm/cvt) are all reverted pending bisection.

using bf16x8 = __attribute__((ext_vector_type(8))) short;   // 8 bf16 = 4 VGPRs
using bf16x4 = __attribute__((ext_vector_type(4))) short;
using f32x4  = __attribute__((ext_vector_type(4))) float;   // MFMA accum

#define MFMA16(a, b, c) __builtin_amdgcn_mfma_f32_16x16x32_bf16((a), (b), (c), 0, 0, 0)

#define SLEN   577
#define NHEAD  12
#define DMODEL 768
#define SPAD   584    // VT row stride in keys: 584*2B = 1168B, 16B-aligned rows
#define NQT    10     // ceil(577/64) q-tiles

static __device__ __forceinline__ bf16x8 zero8() {
    bf16x8 z;
#pragma unroll
    for (int i = 0; i < 8; ++i) z[i] = 0;
    return z;
}

static __device__ __forceinline__ short f2b(float f) {
    return __builtin_bit_cast(short, __float2bfloat16(f));
}

// async global->LDS, 16B per lane. LDS dest is wave-uniform base + lane*16.
static __device__ __forceinline__ void cp16_async(const __hip_bfloat16* g,
                                                  __hip_bfloat16* l) {
    __builtin_amdgcn_global_load_lds(
        (const __attribute__((address_space(1))) unsigned int*)g,
        (__attribute__((address_space(3))) unsigned int*)l,
        16, 0, 0);
}

// fp32 -> bf16, 8 elems/thread/iter, grid-stride. n8 = n/8 (all sizes %8==0).
__global__ __launch_bounds__(256) void cvt_f32_bf16(
    const float* __restrict__ in, __hip_bfloat16* __restrict__ out, int n8)
{
    int i = blockIdx.x * blockDim.x + threadIdx.x;
    const int stride = gridDim.x * blockDim.x;
    for (; i < n8; i += stride) {
        const float4* p = (const float4*)(in + (size_t)i * 8);
        float4 a = p[0], b = p[1];
        float f[8] = {a.x, a.y, a.z, a.w, b.x, b.y, b.z, b.w};
        bf16x8 o;
#pragma unroll
        for (int j = 0; j < 8; ++j) o[j] = f2b(f[j]);
        *(bf16x8*)(out + (size_t)i * 8) = o;
    }
}

// C = A[M,K] @ W[N,K]^T + bias[N]. 128x128 tile, BK=32, 4 waves 2x2.
// m97 structure: linear LDS + global_load_lds w=16, 2 barriers per K-step.
// OMODE 0: bf16 row-major; 1: f32 row-major; 2: bf16 transposed per head into
// VT[((row/577)*768 + col)*SPAD + row%577]  (used for V).
template <int OMODE>
__global__ __launch_bounds__(256) void gemm128_bt(
    const __hip_bfloat16* __restrict__ A,
    const __hip_bfloat16* __restrict__ W,
    const float* __restrict__ bias,
    void* __restrict__ Cout,
    int M, int N, int K)
{
    __shared__ __hip_bfloat16 As[128][32];
    __shared__ __hip_bfloat16 Bs[128][32];

    const int tid  = threadIdx.x;
    const int lane = tid & 63;
    const int wave = tid >> 6;
    const int wm   = (wave >> 1) * 64;
    const int wn   = (wave & 1) * 64;
    const int quad = lane >> 4;
    const int low  = lane & 15;
    const int m0   = blockIdx.x * 128;
    const int n0   = blockIdx.y * 128;

    // staging: each wave-instr covers 16 rows x 32 cols (64 lanes x 16B), linear.
    const int srow = lane >> 2;
    const int scol = (lane & 3) * 8;

    const int ar0 = m0 + wave * 16 + srow;
    const int ar1 = ar0 + 64;
    // clamp OOB rows (last block only): finite garbage, masked at store.
    const __hip_bfloat16* Ag0 = A + (size_t)(ar0 < M ? ar0 : M - 1) * K + scol;
    const __hip_bfloat16* Ag1 = A + (size_t)(ar1 < M ? ar1 : M - 1) * K + scol;
    const __hip_bfloat16* Bg0 = W + (size_t)(n0 + wave * 16 + srow) * K + scol;
    const __hip_bfloat16* Bg1 = Bg0 + (size_t)64 * K;
    __hip_bfloat16* La0 = &As[wave * 16][0];
    __hip_bfloat16* La1 = &As[64 + wave * 16][0];
    __hip_bfloat16* Lb0 = &Bs[wave * 16][0];
    __hip_bfloat16* Lb1 = &Bs[64 + wave * 16][0];

    f32x4 acc[4][4] = {};

    for (int k0 = 0; k0 < K; k0 += 32) {
        cp16_async(Ag0 + k0, La0);
        cp16_async(Ag1 + k0, La1);
        cp16_async(Bg0 + k0, Lb0);
        cp16_async(Bg1 + k0, Lb1);
        __syncthreads();   // drains vmcnt -> staging visible

        bf16x8 af[4], bfv[4];
#pragma unroll
        for (int i = 0; i < 4; ++i)
            af[i] = *(const bf16x8*)&As[wm + i * 16 + low][quad * 8];
#pragma unroll
        for (int j = 0; j < 4; ++j)
            bfv[j] = *(const bf16x8*)&Bs[wn + j * 16 + low][quad * 8];
#pragma unroll
        for (int i = 0; i < 4; ++i)
#pragma unroll
            for (int j = 0; j < 4; ++j)
                acc[i][j] = MFMA16(af[i], bfv[j], acc[i][j]);
        __syncthreads();   // all reads done before next overwrite
    }

    // epilogue: C/D layout col=lane&15, row=quad*4+reg (m89-verified)
#pragma unroll
    for (int j = 0; j < 4; ++j) {
        const int col = n0 + wn + j * 16 + low;
        const float bv = bias[col];
#pragma unroll
        for (int i = 0; i < 4; ++i) {
#pragma unroll
            for (int r = 0; r < 4; ++r) {
                const int row = m0 + wm + i * 16 + quad * 4 + r;
                if (row < M) {
                    const float v = acc[i][j][r] + bv;
                    if constexpr (OMODE == 0) {
                        ((__hip_bfloat16*)Cout)[(size_t)row * N + col] =
                            __float2bfloat16(v);
                    } else if constexpr (OMODE == 1) {
                        ((float*)Cout)[(size_t)row * N + col] = v;
                    } else {
                        const int b = row / SLEN;       // magic-mul div
                        const int s = row - b * SLEN;
                        ((__hip_bfloat16*)Cout)
                            [((size_t)b * DMODEL + col) * SPAD + s] =
                            __float2bfloat16(v);
                    }
                }
            }
        }
    }
}

// Flash attention, swapped-QK^T. Q/K layout [B*S, 768] (head h at cols h*64..);
// V pre-transposed: VT row (bh*64 + d) holds keys 0..576 (stride SPAD).
// Grid 7680 1D, XCD-chunked. Block 256 = 4 waves; wave w owns q rows
// q0+w*16..+15. KVBLK=64.
//
// st[t] = mfma(K_tile_t, Q): i1 (reg axis, quad*4+r) = key, i2 (lane&15) = q.
// Lane (quad,low) reg r holds S[q=low][key = c0 + t*16 + quad*4 + r] -> each
// lane owns 16 scores of ONE q-row; max/sum are in-lane + 2 cross-quad shfl.
__global__ __launch_bounds__(256) void attn_kernel(
    const __hip_bfloat16* __restrict__ Q,
    const __hip_bfloat16* __restrict__ Kk,
    const __hip_bfloat16* __restrict__ VT,
    __hip_bfloat16* __restrict__ O)
{
    const int bid = blockIdx.x;
    const int w   = (bid & 7) * 960 + (bid >> 3);   // 7680 = 8*960, bijective
    const int bh  = w / NQT;
    const int q0  = (w - bh * NQT) * 64;
    const int b   = bh / NHEAD;
    const int h   = bh - b * NHEAD;
    const int tid  = threadIdx.x;
    const int lane = tid & 63;
    const int wave = tid >> 6;
    const int quad = lane >> 4;
    const int low  = lane & 15;

    __shared__ __hip_bfloat16 Ks[64][72];    // keys x d (stride 144B)
    __shared__ __hip_bfloat16 Vt[64][72];    // d x keys (staged linear from VT)
    __shared__ __hip_bfloat16 Ps[4][16][72]; // per-wave P: [q = low][key]

    const size_t base   = (size_t)b * SLEN * DMODEL + (size_t)h * 64;
    const size_t vtbase = (size_t)bh * 64 * SPAD;

    // Q frags (arg2/B-side of the swapped MFMA; per-lane layout same as R1)
    const int qrow = q0 + wave * 16 + low;
    bf16x8 qf0 = zero8(), qf1 = zero8();
    if (qrow < SLEN) {
        qf0 = *(const bf16x8*)(Q + base + (size_t)qrow * DMODEL + quad * 8);
        qf1 = *(const bf16x8*)(Q + base + (size_t)qrow * DMODEL + 32 + quad * 8);
    }

    f32x4 acc[4] = {};       // ctx accum: row q = quad*4+r, col d = low
    float m_run = -1e30f;    // per-lane running max, q = low
    float l_run = 0.f;       // per-lane running denom, q = low

    const int srow = tid >> 2;        // 0..63
    const int sc   = (tid & 3) * 16;  // 16-elem chunk

    for (int c0 = 0; c0 < SLEN; c0 += 64) {
        __syncthreads();   // previous iteration's readers done
        {   // stage K tile: row granularity guard, vector writes
            const int kg = c0 + srow;
            bf16x8 k0v = zero8(), k1v = zero8();
            if (kg < SLEN) {
                const __hip_bfloat16* p = Kk + base + (size_t)kg * DMODEL + sc;
                k0v = *(const bf16x8*)p;
                k1v = *(const bf16x8*)(p + 8);
            }
            *(bf16x8*)&Ks[srow][sc]     = k0v;
            *(bf16x8*)&Ks[srow][sc + 8] = k1v;
        }
        {   // stage V tile straight from VT (already [d][key]) - no transpose
            const __hip_bfloat16* p = VT + vtbase + (size_t)srow * SPAD + c0 + sc;
            bf16x8 v0, v1;
            if (c0 + sc + 15 < SLEN) {
                v0 = *(const bf16x8*)p;
                v1 = *(const bf16x8*)(p + 8);
            } else {            // boundary tile: zero-fill invalid keys
                v0 = zero8(); v1 = zero8();
#pragma unroll
                for (int j = 0; j < 8; ++j) {
                    if (c0 + sc + j < SLEN)
                        v0[j] = __builtin_bit_cast(short, p[j]);
                    if (c0 + sc + 8 + j < SLEN)
                        v1[j] = __builtin_bit_cast(short, p[8 + j]);
                }
            }
            *(bf16x8*)&Vt[srow][sc]     = v0;
            *(bf16x8*)&Vt[srow][sc + 8] = v1;
        }
        __syncthreads();

        // S^T = K Q^T  (A = K rows -> reg axis = key, B = Q rows -> lane = q)
        f32x4 st[4] = {};
#pragma unroll
        for (int t = 0; t < 4; ++t) {
            bf16x8 kf0 = *(const bf16x8*)&Ks[t * 16 + low][quad * 8];
            bf16x8 kf1 = *(const bf16x8*)&Ks[t * 16 + low][32 + quad * 8];
            st[t] = MFMA16(kf0, qf0, st[t]);
            st[t] = MFMA16(kf1, qf1, st[t]);
        }
        // scale + per-key mask (f32, same numerics as R1)
#pragma unroll
        for (int t = 0; t < 4; ++t) {
#pragma unroll
            for (int r = 0; r < 4; ++r) {
                const bool valid = (c0 + t * 16 + quad * 4 + r) < SLEN;
                const float s = st[t][r] * 0.125f;   // 1/sqrt(64)
                st[t][r] = valid ? s : -1e30f;
            }
        }

        // row-max for q=low: in-lane 15-fmax tree + cross-quad butterfly
        float m0v = fmaxf(fmaxf(st[0][0], st[0][1]), fmaxf(st[0][2], st[0][3]));
        float m1v = fmaxf(fmaxf(st[1][0], st[1][1]), fmaxf(st[1][2], st[1][3]));
        float m2v = fmaxf(fmaxf(st[2][0], st[2][1]), fmaxf(st[2][2], st[2][3]));
        float m3v = fmaxf(fmaxf(st[3][0], st[3][1]), fmaxf(st[3][2], st[3][3]));
        float mx  = fmaxf(fmaxf(m0v, m1v), fmaxf(m2v, m3v));
        mx = fmaxf(mx, __shfl_xor(mx, 16));
        mx = fmaxf(mx, __shfl_xor(mx, 32));

        const float mnew  = fmaxf(m_run, mx);
        const float alpha = __expf(m_run - mnew);   // per-lane, q = low
        m_run = mnew;

        // P = exp(st - m), in-lane f32 sum; packed b64 writes Ps[q=low][key]
        float ps = 0.f;
#pragma unroll
        for (int t = 0; t < 4; ++t) {
            bf16x4 pk;
#pragma unroll
            for (int r = 0; r < 4; ++r) {
                const float p = __expf(st[t][r] - mnew);
                ps += p;
                pk[r] = f2b(p);
            }
            *(bf16x4*)&Ps[wave][low][t * 16 + quad * 4] = pk;
        }
        ps += __shfl_xor(ps, 16);
        ps += __shfl_xor(ps, 32);
        l_run = l_run * alpha + ps;

        // rescale acc (rows are q = quad*4+r -> fetch alpha from lane q)
        float av[4];
#pragma unroll
        for (int r = 0; r < 4; ++r) av[r] = __shfl(alpha, quad * 4 + r);
#pragma unroll
        for (int dt = 0; dt < 4; ++dt)
#pragma unroll
            for (int r = 0; r < 4; ++r) acc[dt][r] *= av[r];

        // PV (identical to R1: same-wave LDS round-trip; DS ops in-order)
        bf16x8 pf0 = *(const bf16x8*)&Ps[wave][low][quad * 8];
        bf16x8 pf1 = *(const bf16x8*)&Ps[wave][low][32 + quad * 8];
#pragma unroll
        for (int dt = 0; dt < 4; ++dt) {
            bf16x8 vf0 = *(const bf16x8*)&Vt[dt * 16 + low][quad * 8];
            bf16x8 vf1 = *(const bf16x8*)&Vt[dt * 16 + low][32 + quad * 8];
            acc[dt] = MFMA16(pf0, vf0, acc[dt]);
            acc[dt] = MFMA16(pf1, vf1, acc[dt]);
        }
    }

    // denom lives per-lane at q=low -> transpose to acc layout once
    float lrow[4];
#pragma unroll
    for (int r = 0; r < 4; ++r) lrow[r] = __shfl(l_run, quad * 4 + r);

#pragma unroll
    for (int r = 0; r < 4; ++r) {
        const int row = q0 + wave * 16 + quad * 4 + r;
        if (row < SLEN) {
            const float inv = 1.0f / lrow[r];
#pragma unroll
            for (int dt = 0; dt < 4; ++dt)
                O[((size_t)b * SLEN + row) * DMODEL + h * 64 + dt * 16 + low] =
                    __float2bfloat16(acc[dt][r] * inv);
        }
    }
}

extern "C" void kernel_launch(void* const* d_in, const int* in_sizes, int n_in,
                              void* d_out, int out_size, void* d_ws, size_t ws_size,
                              hipStream_t stream) {
    const float* X  = (const float*)d_in[0];
    const float* Wq = (const float*)d_in[1];
    const float* bq = (const float*)d_in[2];
    const float* Wk = (const float*)d_in[3];
    const float* bk = (const float*)d_in[4];
    const float* Wv = (const float*)d_in[5];
    const float* bv = (const float*)d_in[6];
    const float* Wo = (const float*)d_in[7];
    const float* bo = (const float*)d_in[8];

    const int Bb = 64, S = SLEN, D = DMODEL;
    const int M = Bb * S;                       // 36928
    const size_t szX  = (size_t)M * D;          // 28,311,552
    const size_t szW  = (size_t)D * D;          // 589,824

    // ws layout (bf16): Xb | Wqb | Wkb | Wvb | Wob | Qb | Kb | VTb ; ctx aliases Xb
    __hip_bfloat16* Xb  = (__hip_bfloat16*)d_ws;
    __hip_bfloat16* Wqb = Xb + szX;
    __hip_bfloat16* Wkb = Wqb + szW;
    __hip_bfloat16* Wvb = Wkb + szW;
    __hip_bfloat16* Wob = Wvb + szW;
    __hip_bfloat16* Qb  = Wob + szW;
    __hip_bfloat16* Kb  = Qb + szX;
    __hip_bfloat16* VTb = Kb + szX;
    __hip_bfloat16* Cx  = Xb;                   // reuse after QKV gemms
    float* out = (float*)d_out;

    dim3 blk(256);
    cvt_f32_bf16<<<2048, blk, 0, stream>>>(X, Xb, (int)(szX / 8));
    cvt_f32_bf16<<<288,  blk, 0, stream>>>(Wq, Wqb, (int)(szW / 8));
    cvt_f32_bf16<<<288,  blk, 0, stream>>>(Wk, Wkb, (int)(szW / 8));
    cvt_f32_bf16<<<288,  blk, 0, stream>>>(Wv, Wvb, (int)(szW / 8));
    cvt_f32_bf16<<<288,  blk, 0, stream>>>(Wo, Wob, (int)(szW / 8));

    dim3 gG((M + 127) / 128, D / 128);          // 289 x 6
    gemm128_bt<0><<<gG, blk, 0, stream>>>(Xb, Wqb, bq, (void*)Qb,  M, D, D);
    gemm128_bt<0><<<gG, blk, 0, stream>>>(Xb, Wkb, bk, (void*)Kb,  M, D, D);
    gemm128_bt<2><<<gG, blk, 0, stream>>>(Xb, Wvb, bv, (void*)VTb, M, D, D);

    attn_kernel<<<dim3(Bb * NHEAD * NQT), blk, 0, stream>>>(Qb, Kb, VTb, Cx);

    gemm128_bt<1><<<gG, blk, 0, stream>>>(Cx, Wob, bo, (void*)out, M, D, D);
}

// Round 4
// 744.762 us; speedup vs baseline: 1.4313x; 1.1151x over previous
//
#include <hip/hip_runtime.h>
#include <hip/hip_bf16.h>
#include <cstddef>

// Pipeline (internal math bf16 MFMA, fp32 accum):
//   0)  convert X, Wq..Wo fp32 -> bf16 in ws (biases stay fp32)
//   1)  Q,K = row-major; VT = per-head-transposed V  -- ONE fused QKV gemm
//   2)  flash attention (swapped QK^T, exp2 domain, unmasked 9 tiles + f32
//       tail for key 576) -> ctx (aliases Xb)
//   3)  out = ctx @ Wob^T + bo  (same gemm structure, f32 out)
//
// R4 changes vs R3 (830us: attn 203, gemms ~575):
//   GEMM (the 70% pot): m233 says the 2-phase critical path is the
//   vmcnt(0)-drain at the barrier = latency of the last staged load.
//   (a) QKV fused into one kernel + XCD-chunked n-fastest ordering: one
//       m-panel's 18 n-tiles run adjacent on one XCD -> A-panel L2-resident
//       (drain latency ~900 HBM -> ~200 L2 cyc; A HBM traffic 18x down).
//   (b) BK=64: half the drains/barriers per K. Row stride 128B would be a
//       16-way frag-read conflict -> m173 pattern: LDS stays linear
//       (global_load_lds-legal), global SOURCE chunk is pre-swizzled
//       (c' = c ^ (row&7), 16B units), frag reads XOR the same term.
//       Verified invariant: LDS[r][c] holds A[r][c^(r&7)]; reader wants
//       A[m][ch] -> reads LDS[m][ch^(m&7)] -> A[m][(ch^(m&7))^(m&7)] ✓.
//   ATTN (inspection-safe only): keys 0..575 need no mask -> 9 unmasked
//   tiles + scalar-f32 tail for key 576; exp2 domain via f32 scale
//   0.125*log2e (NOT R2's bf16-Q fold); __any-guarded exact rescale.

using bf16x8 = __attribute__((ext_vector_type(8))) short;   // 8 bf16 = 4 VGPRs
using bf16x4 = __attribute__((ext_vector_type(4))) short;
using f32x4  = __attribute__((ext_vector_type(4))) float;   // MFMA accum

#define MFMA16(a, b, c) __builtin_amdgcn_mfma_f32_16x16x32_bf16((a), (b), (c), 0, 0, 0)

#define SLEN   577
#define NHEAD  12
#define DMODEL 768
#define SPAD   584    // VT row stride in keys: 584*2B = 1168B, 16B-aligned rows
#define NQT    10     // ceil(577/64) q-tiles
#define SCALE2 0.18033688f   // 0.125 * log2(e): softmax in exp2 domain (f32)

static __device__ __forceinline__ bf16x8 zero8() {
    bf16x8 z;
#pragma unroll
    for (int i = 0; i < 8; ++i) z[i] = 0;
    return z;
}

static __device__ __forceinline__ float b2f(short s) {
    return __bfloat162float(__builtin_bit_cast(__hip_bfloat16, s));
}
static __device__ __forceinline__ short f2b(float f) {
    return __builtin_bit_cast(short, __float2bfloat16(f));
}

// m204 bijective XCD-chunk swizzle: consecutive ids land on one XCD.
static __device__ __forceinline__ int xcd_swizzle(int bid, int nwg) {
    const int xcd = bid & 7, idx = bid >> 3;
    const int q = nwg >> 3, r = nwg & 7;
    return (xcd < r ? xcd * (q + 1) : r * (q + 1) + (xcd - r) * q) + idx;
}

// async global->LDS, 16B per lane. LDS dest is wave-uniform base + lane*16.
static __device__ __forceinline__ void cp16_async(const __hip_bfloat16* g,
                                                  __hip_bfloat16* l) {
    __builtin_amdgcn_global_load_lds(
        (const __attribute__((address_space(1))) unsigned int*)g,
        (__attribute__((address_space(3))) unsigned int*)l,
        16, 0, 0);
}

// fp32 -> bf16, 8 elems/thread/iter, grid-stride. n8 = n/8 (all sizes %8==0).
__global__ __launch_bounds__(256) void cvt_f32_bf16(
    const float* __restrict__ in, __hip_bfloat16* __restrict__ out, int n8)
{
    int i = blockIdx.x * blockDim.x + threadIdx.x;
    const int stride = gridDim.x * blockDim.x;
    for (; i < n8; i += stride) {
        const float4* p = (const float4*)(in + (size_t)i * 8);
        float4 a = p[0], b = p[1];
        float f[8] = {a.x, a.y, a.z, a.w, b.x, b.y, b.z, b.w};
        bf16x8 o;
#pragma unroll
        for (int j = 0; j < 8; ++j) o[j] = f2b(f[j]);
        *(bf16x8*)(out + (size_t)i * 8) = o;
    }
}

// MODE 0: fused QKV (3 weight sets; sub 0,1 -> bf16 row-major; sub 2 -> VT
//         per-head transpose). MODE 1: single output, f32 row-major.
// 128x128 tile, BK=64, 4 waves 2x2. Linear LDS [128][64] + global_load_lds
// w=16 with source-chunk swizzle (see header comment). 1D grid, XCD-chunked,
// n-fastest: the nTot n-tiles of one m-panel are dispatch-adjacent.
template <int MODE>
__global__ __launch_bounds__(256) void gemm_bk64(
    const __hip_bfloat16* __restrict__ A,
    const __hip_bfloat16* __restrict__ W0,
    const __hip_bfloat16* __restrict__ W1,
    const __hip_bfloat16* __restrict__ W2,
    const float* __restrict__ bias0,
    const float* __restrict__ bias1,
    const float* __restrict__ bias2,
    void* __restrict__ O0, void* __restrict__ O1, void* __restrict__ O2,
    int M, int N, int K)
{
    __shared__ __hip_bfloat16 As[128][64];
    __shared__ __hip_bfloat16 Bs[128][64];

    const int NSUB = (MODE == 0) ? 3 : 1;
    const int NT   = N / 128;                     // 6
    const int nTot = NT * NSUB;
    const int id   = xcd_swizzle(blockIdx.x, gridDim.x);
    const int m0   = (id / nTot) * 128;
    const int nn   = id % nTot;
    const int sub  = nn / NT;
    const int n0   = (nn % NT) * 128;
    const __hip_bfloat16* W = sub == 0 ? W0 : (sub == 1 ? W1 : W2);
    const float* bias       = sub == 0 ? bias0 : (sub == 1 ? bias1 : bias2);
    void* C                 = sub == 0 ? O0 : (sub == 1 ? O1 : O2);

    const int tid  = threadIdx.x;
    const int lane = tid & 63;
    const int wave = tid >> 6;
    const int wm   = (wave >> 1) * 64;
    const int wn   = (wave & 1) * 64;
    const int quad = lane >> 4;
    const int low  = lane & 15;

    // staging geometry: per call-site c (0..3), wave covers rows
    // c*32 + wave*8 + (lane>>3); lane's 16B chunk index is swizzled:
    // LDS[r][ch] holds global chunk ch ^ (r&7); here r&7 == lane>>3.
    const int g    = lane >> 3;               // row-within-8 == r&7
    const int swzc = (lane & 7) ^ g;          // source chunk for this lane

    const __hip_bfloat16* Ag[4];
    const __hip_bfloat16* Bg[4];
    __hip_bfloat16* La[4];
    __hip_bfloat16* Lb[4];
#pragma unroll
    for (int c = 0; c < 4; ++c) {
        int ra = m0 + c * 32 + wave * 8 + g;
        if (ra >= M) ra = M - 1;              // clamp: garbage masked at store
        const int rb = n0 + c * 32 + wave * 8 + g;     // always < N
        Ag[c] = A + (size_t)ra * K + swzc * 8;
        Bg[c] = W + (size_t)rb * K + swzc * 8;
        La[c] = &As[0][0] + c * 2048 + wave * 512;
        Lb[c] = &Bs[0][0] + c * 2048 + wave * 512;
    }

    f32x4 acc[4][4] = {};

    for (int k0 = 0; k0 < K; k0 += 64) {
#pragma unroll
        for (int c = 0; c < 4; ++c) {
            cp16_async(Ag[c] + k0, La[c]);
            cp16_async(Bg[c] + k0, Lb[c]);
        }
        __syncthreads();   // drains vmcnt -> staging visible

#pragma unroll
        for (int ks = 0; ks < 2; ++ks) {
            const int ch = ((quad + ks * 4) ^ (low & 7)) * 8;  // swizzled read
            bf16x8 af[4], bfv[4];
#pragma unroll
            for (int i = 0; i < 4; ++i)
                af[i] = *(const bf16x8*)&As[wm + i * 16 + low][ch];
#pragma unroll
            for (int j = 0; j < 4; ++j)
                bfv[j] = *(const bf16x8*)&Bs[wn + j * 16 + low][ch];
#pragma unroll
            for (int i = 0; i < 4; ++i)
#pragma unroll
                for (int j = 0; j < 4; ++j)
                    acc[i][j] = MFMA16(af[i], bfv[j], acc[i][j]);
        }
        __syncthreads();   // all reads done before next overwrite
    }

    // epilogue: C/D layout col=lane&15, row=quad*4+reg (m89-verified)
#pragma unroll
    for (int j = 0; j < 4; ++j) {
        const int col = n0 + wn + j * 16 + low;
        const float bv = bias[col];
#pragma unroll
        for (int i = 0; i < 4; ++i) {
#pragma unroll
            for (int r = 0; r < 4; ++r) {
                const int row = m0 + wm + i * 16 + quad * 4 + r;
                if (row < M) {
                    const float v = acc[i][j][r] + bv;
                    if constexpr (MODE == 1) {
                        ((float*)C)[(size_t)row * N + col] = v;
                    } else {
                        if (sub < 2) {
                            ((__hip_bfloat16*)C)[(size_t)row * N + col] =
                                __float2bfloat16(v);
                        } else {           // V -> per-head transpose
                            const int bb = row / SLEN;
                            const int s  = row - bb * SLEN;
                            ((__hip_bfloat16*)C)
                                [((size_t)bb * DMODEL + col) * SPAD + s] =
                                __float2bfloat16(v);
                        }
                    }
                }
            }
        }
    }
}

// Flash attention, swapped-QK^T, exp2 domain. Q/K layout [B*S,768] (head h at
// cols h*64..); V pre-transposed: VT row (bh*64+d) holds keys 0..576 (stride
// SPAD). Grid 7680 1D XCD-chunked. Block 256 = 4 waves; wave w owns q rows
// q0+w*16..+15. KVBLK=64; 9 unmasked tiles (keys 0..575) + f32 tail (key 576).
//
// st[t] = mfma(K_t, Q): lane (quad,low) reg r holds S[q=low][key=16t+quad*4+r]
// -> in-lane max tree + 2 cross-quad shfl; denom summed in-lane.
__global__ __launch_bounds__(256) void attn_kernel(
    const __hip_bfloat16* __restrict__ Q,
    const __hip_bfloat16* __restrict__ Kk,
    const __hip_bfloat16* __restrict__ VT,
    __hip_bfloat16* __restrict__ O)
{
    const int bid = blockIdx.x;
    const int w   = (bid & 7) * 960 + (bid >> 3);   // 7680 = 8*960, bijective
    const int bh  = w / NQT;
    const int q0  = (w - bh * NQT) * 64;
    const int b   = bh / NHEAD;
    const int h   = bh - b * NHEAD;
    const int tid  = threadIdx.x;
    const int lane = tid & 63;
    const int wave = tid >> 6;
    const int quad = lane >> 4;
    const int low  = lane & 15;

    __shared__ __hip_bfloat16 Ks[64][72];    // keys x d (stride 144B)
    __shared__ __hip_bfloat16 Vt[64][72];    // d x keys (staged linear from VT)
    __shared__ __hip_bfloat16 Ps[4][16][72]; // per-wave P: [q = low][key]

    const size_t base   = (size_t)b * SLEN * DMODEL + (size_t)h * 64;
    const size_t vtbase = (size_t)bh * 64 * SPAD;

    // Q frags (arg2/B-side of the swapped MFMA)
    const int qrow = q0 + wave * 16 + low;
    bf16x8 qf0 = zero8(), qf1 = zero8();
    if (qrow < SLEN) {
        qf0 = *(const bf16x8*)(Q + base + (size_t)qrow * DMODEL + quad * 8);
        qf1 = *(const bf16x8*)(Q + base + (size_t)qrow * DMODEL + 32 + quad * 8);
    }

    f32x4 acc[4] = {};       // ctx accum: row q = quad*4+r, col d = low
    float m_run = -1e30f;    // per-lane running max (log2 units), q = low
    float l_run = 0.f;       // per-lane running denom, q = low

    const int srow = tid >> 2;        // 0..63
    const int sc   = (tid & 3) * 16;  // 16-elem chunk

    for (int c0 = 0; c0 < 576; c0 += 64) {   // keys 0..575: no masking needed
        __syncthreads();   // previous iteration's readers done
        {   // stage K rows + V rows (both fully in-bounds here)
            const __hip_bfloat16* kp = Kk + base + (size_t)(c0 + srow) * DMODEL + sc;
            *(bf16x8*)&Ks[srow][sc]     = *(const bf16x8*)kp;
            *(bf16x8*)&Ks[srow][sc + 8] = *(const bf16x8*)(kp + 8);
            const __hip_bfloat16* vp = VT + vtbase + (size_t)srow * SPAD + c0 + sc;
            *(bf16x8*)&Vt[srow][sc]     = *(const bf16x8*)vp;
            *(bf16x8*)&Vt[srow][sc + 8] = *(const bf16x8*)(vp + 8);
        }
        __syncthreads();

        // S^T = K Q^T  (A = K rows -> reg axis = key, B = Q rows -> lane = q)
        f32x4 st[4] = {};
#pragma unroll
        for (int t = 0; t < 4; ++t) {
            bf16x8 kf0 = *(const bf16x8*)&Ks[t * 16 + low][quad * 8];
            bf16x8 kf1 = *(const bf16x8*)&Ks[t * 16 + low][32 + quad * 8];
            st[t] = MFMA16(kf0, qf0, st[t]);
            st[t] = MFMA16(kf1, qf1, st[t]);
        }
#pragma unroll
        for (int t = 0; t < 4; ++t)
#pragma unroll
            for (int r = 0; r < 4; ++r)
                st[t][r] *= SCALE2;             // log2 domain, no mask

        // row-max for q=low: in-lane 15-fmax tree + cross-quad butterfly
        float m0v = fmaxf(fmaxf(st[0][0], st[0][1]), fmaxf(st[0][2], st[0][3]));
        float m1v = fmaxf(fmaxf(st[1][0], st[1][1]), fmaxf(st[1][2], st[1][3]));
        float m2v = fmaxf(fmaxf(st[2][0], st[2][1]), fmaxf(st[2][2], st[2][3]));
        float m3v = fmaxf(fmaxf(st[3][0], st[3][1]), fmaxf(st[3][2], st[3][3]));
        float mx  = fmaxf(fmaxf(m0v, m1v), fmaxf(m2v, m3v));
        mx = fmaxf(mx, __shfl_xor(mx, 16));
        mx = fmaxf(mx, __shfl_xor(mx, 32));

        // exact guarded rescale (skipped iff every lane's alpha == 1)
        if (__any(mx > m_run)) {
            const float mnew  = fmaxf(m_run, mx);
            const float alpha = exp2f(m_run - mnew);
            m_run = mnew;
            l_run *= alpha;
            float av[4];
#pragma unroll
            for (int r = 0; r < 4; ++r) av[r] = __shfl(alpha, quad * 4 + r);
#pragma unroll
            for (int dt = 0; dt < 4; ++dt)
#pragma unroll
                for (int r = 0; r < 4; ++r) acc[dt][r] *= av[r];
        }

        // P = exp2(st - m), in-lane f32 sum; packed b64 writes Ps[q=low][key]
        float ps = 0.f;
#pragma unroll
        for (int t = 0; t < 4; ++t) {
            bf16x4 pk;
#pragma unroll
            for (int r = 0; r < 4; ++r) {
                const float p = exp2f(st[t][r] - m_run);
                ps += p;
                pk[r] = f2b(p);
            }
            *(bf16x4*)&Ps[wave][low][t * 16 + quad * 4] = pk;
        }
        ps += __shfl_xor(ps, 16);
        ps += __shfl_xor(ps, 32);
        l_run += ps;

        // PV (same-wave LDS round-trip; DS ops in-order)
        bf16x8 pf0 = *(const bf16x8*)&Ps[wave][low][quad * 8];
        bf16x8 pf1 = *(const bf16x8*)&Ps[wave][low][32 + quad * 8];
#pragma unroll
        for (int dt = 0; dt < 4; ++dt) {
            bf16x8 vf0 = *(const bf16x8*)&Vt[dt * 16 + low][quad * 8];
            bf16x8 vf1 = *(const bf16x8*)&Vt[dt * 16 + low][32 + quad * 8];
            acc[dt] = MFMA16(pf0, vf0, acc[dt]);
            acc[dt] = MFMA16(pf1, vf1, acc[dt]);
        }
    }

    // ---- tail: key 576, scalar f32 path ----
    {
        const __hip_bfloat16* kp = Kk + base + (size_t)576 * DMODEL;
        bf16x8 k0 = *(const bf16x8*)(kp + quad * 8);
        bf16x8 k1 = *(const bf16x8*)(kp + 32 + quad * 8);
        float d = 0.f;
#pragma unroll
        for (int j = 0; j < 8; ++j)
            d += b2f(qf0[j]) * b2f(k0[j]) + b2f(qf1[j]) * b2f(k1[j]);
        d += __shfl_xor(d, 16);
        d += __shfl_xor(d, 32);
        const float s = d * SCALE2;             // score for (q=low, key 576)
        if (__any(s > m_run)) {
            const float mnew  = fmaxf(m_run, s);
            const float alpha = exp2f(m_run - mnew);
            m_run = mnew;
            l_run *= alpha;
            float av[4];
#pragma unroll
            for (int r = 0; r < 4; ++r) av[r] = __shfl(alpha, quad * 4 + r);
#pragma unroll
            for (int dt = 0; dt < 4; ++dt)
#pragma unroll
                for (int r = 0; r < 4; ++r) acc[dt][r] *= av[r];
        }
        const float p = exp2f(s - m_run);
        l_run += p;
        float pq[4];
#pragma unroll
        for (int r = 0; r < 4; ++r) pq[r] = __shfl(p, quad * 4 + r);
#pragma unroll
        for (int dt = 0; dt < 4; ++dt) {
            const float vv = __bfloat162float(
                VT[vtbase + (size_t)(dt * 16 + low) * SPAD + 576]);
#pragma unroll
            for (int r = 0; r < 4; ++r) acc[dt][r] += pq[r] * vv;
        }
    }

    // denom lives per-lane at q=low -> transpose to acc layout once
    float lrow[4];
#pragma unroll
    for (int r = 0; r < 4; ++r) lrow[r] = __shfl(l_run, quad * 4 + r);

#pragma unroll
    for (int r = 0; r < 4; ++r) {
        const int row = q0 + wave * 16 + quad * 4 + r;
        if (row < SLEN) {
            const float inv = 1.0f / lrow[r];
#pragma unroll
            for (int dt = 0; dt < 4; ++dt)
                O[((size_t)b * SLEN + row) * DMODEL + h * 64 + dt * 16 + low] =
                    __float2bfloat16(acc[dt][r] * inv);
        }
    }
}

extern "C" void kernel_launch(void* const* d_in, const int* in_sizes, int n_in,
                              void* d_out, int out_size, void* d_ws, size_t ws_size,
                              hipStream_t stream) {
    const float* X  = (const float*)d_in[0];
    const float* Wq = (const float*)d_in[1];
    const float* bq = (const float*)d_in[2];
    const float* Wk = (const float*)d_in[3];
    const float* bk = (const float*)d_in[4];
    const float* Wv = (const float*)d_in[5];
    const float* bv = (const float*)d_in[6];
    const float* Wo = (const float*)d_in[7];
    const float* bo = (const float*)d_in[8];

    const int Bb = 64, S = SLEN, D = DMODEL;
    const int M = Bb * S;                       // 36928
    const size_t szX  = (size_t)M * D;          // 28,311,552
    const size_t szW  = (size_t)D * D;          // 589,824

    // ws layout (bf16): Xb | Wqb | Wkb | Wvb | Wob | Qb | Kb | VTb ; ctx aliases Xb
    __hip_bfloat16* Xb  = (__hip_bfloat16*)d_ws;
    __hip_bfloat16* Wqb = Xb + szX;
    __hip_bfloat16* Wkb = Wqb + szW;
    __hip_bfloat16* Wvb = Wkb + szW;
    __hip_bfloat16* Wob = Wvb + szW;
    __hip_bfloat16* Qb  = Wob + szW;
    __hip_bfloat16* Kb  = Qb + szX;
    __hip_bfloat16* VTb = Kb + szX;
    __hip_bfloat16* Cx  = Xb;                   // reuse after QKV gemm
    float* out = (float*)d_out;

    dim3 blk(256);
    cvt_f32_bf16<<<2048, blk, 0, stream>>>(X, Xb, (int)(szX / 8));
    cvt_f32_bf16<<<288,  blk, 0, stream>>>(Wq, Wqb, (int)(szW / 8));
    cvt_f32_bf16<<<288,  blk, 0, stream>>>(Wk, Wkb, (int)(szW / 8));
    cvt_f32_bf16<<<288,  blk, 0, stream>>>(Wv, Wvb, (int)(szW / 8));
    cvt_f32_bf16<<<288,  blk, 0, stream>>>(Wo, Wob, (int)(szW / 8));

    const int mTiles = (M + 127) / 128;         // 289
    gemm_bk64<0><<<dim3(mTiles * 18), blk, 0, stream>>>(
        Xb, Wqb, Wkb, Wvb, bq, bk, bv,
        (void*)Qb, (void*)Kb, (void*)VTb, M, D, D);

    attn_kernel<<<dim3(Bb * NHEAD * NQT), blk, 0, stream>>>(Qb, Kb, VTb, Cx);

    gemm_bk64<1><<<dim3(mTiles * 6), blk, 0, stream>>>(
        Cx, Wob, Wob, Wob, bo, bo, bo,
        (void*)out, (void*)out, (void*)out, M, D, D);
}